// Round 1
// 293.769 us; speedup vs baseline: 1.0898x; 1.0898x over previous
//
#include <hip/hip_runtime.h>
#include <stdint.h>
#include <math.h>

#define T_DIM 8192
#define D_DIM 4096
#define E_DIM 64
#define TE (T_DIM * E_DIM)  // 524288
#define GAP_MARGIN 4e-3     // > 2x provable worst-case bf16-split logit error (9.4e-4)
#define BK 128              // K elements per chunk
#define NCHUNK (D_DIM / BK) // 32
#define KSTEPS (BK / 32)    // 4 MFMA k-steps per chunk
#define ROWS 16             // rows per block

typedef __attribute__((ext_vector_type(8))) short short8_t;  // 8 bf16 (4 VGPRs)
typedef __attribute__((ext_vector_type(4))) float f32x4;

// ============================================================================
// W bf16 hi/lo planes in fragment-linear chunk order, filled once per call by
// w_split_kernel. Layout: idx = ch*8192 + s*2048 + subE*512 + q*128 + ee*8 + j
// where e = subE*16+ee, k = ch*128 + s*32 + q*8 + j. This makes the per-wave
// B-fragment read (lane n=lane&15, koct=lane>>4) a fully-coalesced 1KB
// global_load_dwordx4 per wave — B never touches LDS.
// ============================================================================
__device__ __align__(16) short Whi_g[E_DIM * D_DIM];  // 512 KB
__device__ __align__(16) short Wlo_g[E_DIM * D_DIM];  // 512 KB

// ============================================================================
// Threefry-2x32, key = (0, 42), 20 rounds — VALIDATED (prior session r3/4/5)
// ============================================================================
__device__ __forceinline__ void threefry2x32_k42(uint32_t x0, uint32_t x1,
                                                 uint32_t& o0, uint32_t& o1) {
  const uint32_t ks0 = 0u, ks1 = 42u;
  const uint32_t ks2 = 0x1BD11BDAu ^ ks0 ^ ks1;
  x0 += ks0; x1 += ks1;
#define TF_RND(r) { x0 += x1; x1 = (x1 << (r)) | (x1 >> (32 - (r))); x1 ^= x0; }
  TF_RND(13) TF_RND(15) TF_RND(26) TF_RND(6)   x0 += ks1; x1 += ks2 + 1u;
  TF_RND(17) TF_RND(29) TF_RND(16) TF_RND(24)  x0 += ks2; x1 += ks0 + 2u;
  TF_RND(13) TF_RND(15) TF_RND(26) TF_RND(6)   x0 += ks0; x1 += ks1 + 3u;
  TF_RND(17) TF_RND(29) TF_RND(16) TF_RND(24)  x0 += ks1; x1 += ks2 + 4u;
  TF_RND(13) TF_RND(15) TF_RND(26) TF_RND(6)   x0 += ks2; x1 += ks0 + 5u;
#undef TF_RND
  o0 = x0; o1 = x1;
}

__device__ __forceinline__ uint32_t jax_random_bits32(uint32_t j) {
  uint32_t o0, o1;
  threefry2x32_k42(0u, j, o0, o1);
  return o0 ^ o1;
}

// f64 finalize per row (lane = expert) — VALIDATED, unchanged
__device__ __forceinline__ void finalize_row_f64(double logit, int e, int t,
                                                 float& mask_out, float& weight_out,
                                                 double& gap_out) {
  double m = logit;
#pragma unroll
  for (int off = 1; off < 64; off <<= 1) {
    const double om = __shfl_xor(m, off, 64);
    m = (om > m) ? om : m;
  }
  const double pe = exp(logit - m);
  double s = pe;
#pragma unroll
  for (int off = 1; off < 64; off <<= 1) s += __shfl_xor(s, off, 64);
  weight_out = (float)(pe / s);

  const int idx = t * 64 + e;
  const uint32_t bits = jax_random_bits32((uint32_t)idx);
  const float f01 = __uint_as_float((bits >> 9) | 0x3f800000u) - 1.0f;
  const float minv = 1e-6f;
  const float maxv = 0.999999f;
  float u = __fadd_rn(__fmul_rn(f01, maxv - minv), minv);
  u = fmaxf(minv, u);
  const double g = -log(-log((double)u));
  const double sel = logit + g;

  float mask = 0.0f;
  double cur = sel;
  double v8 = 0.0, v9 = 0.0;
  for (int it = 0; it < 9; ++it) {
    double v = cur;
    int vi = e;
#pragma unroll
    for (int off = 1; off < 64; off <<= 1) {
      const double ov = __shfl_xor(v, off, 64);
      const int    oi = __shfl_xor(vi, off, 64);
      if (ov > v || (ov == v && oi < vi)) { v = ov; vi = oi; }
    }
    if (it < 8) {
      if (vi == e) { mask = 1.0f; cur = -__builtin_inf(); }
      if (it == 7) v8 = v;
    } else {
      v9 = v;
    }
  }
  mask_out = mask;
  gap_out = v8 - v9;
}

// fp32 -> bf16 (RNE, finite inputs only)
__device__ __forceinline__ uint16_t f2bf(float f) {
  const uint32_t x = __float_as_uint(f);
  return (uint16_t)((x + 0x7FFFu + ((x >> 16) & 1u)) >> 16);
}

// split 8 consecutive floats into bf16 hi/lo short8 fragments
__device__ __forceinline__ void split8(const float4 a, const float4 b,
                                       short8_t& hi, short8_t& lo) {
  const float f[8] = {a.x, a.y, a.z, a.w, b.x, b.y, b.z, b.w};
#pragma unroll
  for (int j = 0; j < 8; ++j) {
    const uint16_t hb = f2bf(f[j]);
    const float fh = __uint_as_float((uint32_t)hb << 16);
    const uint16_t lb = f2bf(f[j] - fh);
    hi[j] = (short)hb;
    lo[j] = (short)lb;
  }
}

// ============================================================================
// Pre-kernel: split W (fp32, 1 MB) into bf16 hi/lo planes, fragment-linear.
// 64 blocks x 256 threads, 2 units (8 k each) per thread. ~1 MB read, 2 MB
// written; runs once per call (~4 us). Uses the SAME f2bf split as the main
// kernel, so numerics are identical to the validated in-kernel split.
// ============================================================================
__global__ __launch_bounds__(256)
void w_split_kernel(const float* __restrict__ W) {
  const int g = blockIdx.x * 256 + threadIdx.x;  // 0..16383
#pragma unroll
  for (int r = 0; r < 2; ++r) {
    const int u = g * 2 + r;        // unit id 0..32767 (one unit = 8 k of one e)
    const int e = u >> 9;           // 512 k-octets per expert
    const int k0 = (u & 511) * 8;
    const float* wp = W + (size_t)e * D_DIM + k0;
    const float4 a = *reinterpret_cast<const float4*>(wp);
    const float4 b = *reinterpret_cast<const float4*>(wp + 4);
    short8_t hi, lo;
    split8(a, b, hi, lo);
    const int ch = k0 >> 7, s = (k0 >> 5) & 3, q = (k0 >> 3) & 3;
    const int subE = e >> 4, ee = e & 15;
    const int idx = ch * 8192 + s * 2048 + subE * 512 + q * 128 + ee * 8;
    *reinterpret_cast<short8_t*>(Whi_g + idx) = hi;
    *reinterpret_cast<short8_t*>(Wlo_g + idx) = lo;
  }
}

// ============================================================================
// MFMA router kernel. 512 blocks x 256 threads (4 waves). Block: 16 rows x 64 e.
// Wave w = n_sub (0..3) -> C 16x16 tile via mfma_f32_16x16x32_bf16 with the
// validated 3-product bf16-split (Alo*Bhi + Ahi*Blo + Ahi*Bhi, same order).
//
// A: h rows split in-register (each thread owns one 16B unit = 8 k of 1 row),
//    stored to double-buffered LDS planes with XOR swizzle unit^=(unit>>4)&7.
//    Write: every bank hit exactly 8x per wave b128 (HW minimum, conflict-free).
//    Read (u = s*64+lane, same XOR): 2 words/bank per 16-lane phase (minimum).
// B: loaded straight from the precomputed fragment-linear global planes into
//    registers — fully coalesced, L2-resident, zero LDS, zero conversion.
// One barrier per chunk (A double-buffered); A prefetch issued AFTER the
// barrier so no vmcnt(0) drain sits between issue and use.
// LDS total ~20 KB -> 2 independent blocks/CU (vs 1 barrier-locked before).
// ============================================================================
__global__ __launch_bounds__(256, 2)
void router_mfma_kernel(const float* __restrict__ h,
                        const float* __restrict__ bias,
                        float* __restrict__ out,
                        unsigned char* __restrict__ flags) {
  __shared__ __align__(16) short Ahi[2][KSTEPS * 512];  // 2 x 4 KB
  __shared__ __align__(16) short Alo[2][KSTEPS * 512];  // 2 x 4 KB
  __shared__ float logits_lds[ROWS * 65];               // 4.2 KB, +1 pad

  const int tid  = threadIdx.x;
  const int wave = tid >> 6;   // n_sub
  const int lane = tid & 63;
  const int row0 = blockIdx.x * ROWS;

  // A staging: thread owns (row = tid>>4, k-octet = tid&15) of each chunk
  const int a_row  = tid >> 4;
  const int a_koct = tid & 15;
  const int a_s = a_koct >> 2, a_q = a_koct & 3;
  const int u_w0 = a_s * 64 + a_q * 16 + a_row;
  const int u_w  = u_w0 ^ ((u_w0 >> 4) & 7);   // bank-conflict-free swizzle
  const int a_widx = u_w * 8;
  const float* hrow = h + (size_t)(row0 + a_row) * D_DIM + a_koct * 8;

  // B fragment base: e = wave*16 + (lane&15), k-octet-in-kstep = lane>>4
  const int b_off = wave * 512 + (lane >> 4) * 128 + (lane & 15) * 8;

  f32x4 acc = {0.0f, 0.0f, 0.0f, 0.0f};

  float4 pa0 = *reinterpret_cast<const float4*>(hrow);
  float4 pa1 = *reinterpret_cast<const float4*>(hrow + 4);

  int buf = 0;
  for (int ch = 0; ch < NCHUNK; ++ch) {
    // split prefetched A -> swizzled LDS planes (one b128 per plane)
    short8_t hi, lo;
    split8(pa0, pa1, hi, lo);
    *reinterpret_cast<short8_t*>(&Ahi[buf][a_widx]) = hi;
    *reinterpret_cast<short8_t*>(&Alo[buf][a_widx]) = lo;
    __syncthreads();

    // prefetch next chunk's A AFTER the barrier: latency hides under MFMA
    if (ch + 1 < NCHUNK) {
      const float* p = hrow + (size_t)(ch + 1) * BK;
      pa0 = *reinterpret_cast<const float4*>(p);
      pa1 = *reinterpret_cast<const float4*>(p + 4);
    }

    const short* bhp = Whi_g + (size_t)ch * 8192 + b_off;
    const short* blp = Wlo_g + (size_t)ch * 8192 + b_off;
#pragma unroll
    for (int s = 0; s < KSTEPS; ++s) {
      const int ur0 = s * 64 + lane;
      const int ur  = ur0 ^ ((ur0 >> 4) & 7);
      const short8_t ah = *reinterpret_cast<const short8_t*>(&Ahi[buf][ur * 8]);
      const short8_t al = *reinterpret_cast<const short8_t*>(&Alo[buf][ur * 8]);
      const short8_t bh = *reinterpret_cast<const short8_t*>(bhp + s * 2048);
      const short8_t bl = *reinterpret_cast<const short8_t*>(blp + s * 2048);
      acc = __builtin_amdgcn_mfma_f32_16x16x32_bf16(al, bh, acc, 0, 0, 0);
      acc = __builtin_amdgcn_mfma_f32_16x16x32_bf16(ah, bl, acc, 0, 0, 0);
      acc = __builtin_amdgcn_mfma_f32_16x16x32_bf16(ah, bh, acc, 0, 0, 0);
    }
    buf ^= 1;
  }

  // epilogue: C/D layout col=lane&15, row=(lane>>4)*4+reg -> logits LDS
  {
    const int q   = lane >> 4;
    const int col = wave * 16 + (lane & 15);
#pragma unroll
    for (int reg = 0; reg < 4; ++reg) {
      const int m = q * 4 + reg;
      logits_lds[m * 65 + col] = acc[reg];
    }
  }
  __syncthreads();

  // finalize: wave handles rows 4*wave..+3, lane = expert — VALIDATED path
  const int e = lane;
  const double be = (double)bias[e];
  for (int rr = 0; rr < 4; ++rr) {
    const int rloc = wave * 4 + rr;
    const int t = row0 + rloc;
    const double logit = (double)logits_lds[rloc * 65 + e] + be;

    float mask, weight;
    double gap;
    finalize_row_f64(logit, e, t, mask, weight, gap);

    const int idx = t * 64 + e;
    out[idx]          = mask;
    out[TE + idx]     = weight;
    out[2 * TE + idx] = (float)logit;
    if (e == 0) flags[t] = (gap < GAP_MARGIN) ? 1 : 0;
  }
}

// ============================================================================
// Fixup kernel — VALIDATED logic; expert loop unrolled 4-wide to break the
// serial f64 FMA + shuffle-reduce dependency chain (same per-expert sums).
// ============================================================================
__global__ __launch_bounds__(256)
void router_fixup_kernel(const float* __restrict__ h,
                         const float* __restrict__ W,
                         const float* __restrict__ bias,
                         const unsigned char* __restrict__ flags,
                         float* __restrict__ out) {
  const int t = blockIdx.x;
  if (flags[t] == 0) return;

  __shared__ double red[4][64];

  const int tid  = threadIdx.x;
  const int wv   = tid >> 6;
  const int lane = tid & 63;

  const float* hrow = h + (size_t)t * D_DIM + wv * 1024;

  float hv[16];
#pragma unroll
  for (int j = 0; j < 16; ++j) hv[j] = hrow[j * 64 + lane];

  for (int e0 = 0; e0 < 64; e0 += 4) {
    const float* w0 = W + (size_t)(e0 + 0) * D_DIM + wv * 1024;
    const float* w1 = W + (size_t)(e0 + 1) * D_DIM + wv * 1024;
    const float* w2 = W + (size_t)(e0 + 2) * D_DIM + wv * 1024;
    const float* w3 = W + (size_t)(e0 + 3) * D_DIM + wv * 1024;
    double a0 = 0.0, a1 = 0.0, a2 = 0.0, a3 = 0.0;
#pragma unroll
    for (int j = 0; j < 16; ++j) {
      const double hd = (double)hv[j];
      a0 = fma((double)w0[j * 64 + lane], hd, a0);
      a1 = fma((double)w1[j * 64 + lane], hd, a1);
      a2 = fma((double)w2[j * 64 + lane], hd, a2);
      a3 = fma((double)w3[j * 64 + lane], hd, a3);
    }
#pragma unroll
    for (int off = 1; off < 64; off <<= 1) {
      a0 += __shfl_xor(a0, off, 64);
      a1 += __shfl_xor(a1, off, 64);
      a2 += __shfl_xor(a2, off, 64);
      a3 += __shfl_xor(a3, off, 64);
    }
    if (lane == e0 + 0) red[wv][lane] = a0;
    if (lane == e0 + 1) red[wv][lane] = a1;
    if (lane == e0 + 2) red[wv][lane] = a2;
    if (lane == e0 + 3) red[wv][lane] = a3;
  }
  __syncthreads();

  if (wv == 0) {
    const int e = lane;
    const double logit = ((red[0][e] + red[1][e]) + (red[2][e] + red[3][e]))
                         + (double)bias[e];
    float mask, weight;
    double gap;
    finalize_row_f64(logit, e, t, mask, weight, gap);

    const int idx = t * 64 + e;
    out[idx]          = mask;
    out[TE + idx]     = weight;
    out[2 * TE + idx] = (float)logit;
  }
}

extern "C" void kernel_launch(void* const* d_in, const int* in_sizes, int n_in,
                              void* d_out, int out_size, void* d_ws, size_t ws_size,
                              hipStream_t stream) {
  const float* h    = (const float*)d_in[0];
  const float* W    = (const float*)d_in[1];
  const float* bias = (const float*)d_in[2];
  // d_in[3] = k (always 8) — hard-coded top-8
  float* out = (float*)d_out;
  unsigned char* flags = (unsigned char*)d_ws;  // 8192 B, fully rewritten per call

  w_split_kernel<<<64, 256, 0, stream>>>(W);
  router_mfma_kernel<<<T_DIM / ROWS, 256, 0, stream>>>(h, bias, out, flags);
  router_fixup_kernel<<<T_DIM, 256, 0, stream>>>(h, W, bias, flags, out);
}